// Round 18
// baseline (114.334 us; speedup 1.0000x reference)
//
#include <hip/hip_runtime.h>
#include <stdint.h>

#define N_NODES 50000
#define N_EDGES 800000
#define D_IN    256
#define D_H     64
#define D_O     40

// CSR build geometry: 256 blocks x 3125-edge slices; ONE pass -- u8 counts
// packed 4-per-u32 in 50 KB LDS cover all 50000 nodes.
#define NB_H   256
#define NT_H   512
#define EPB    (N_EDGES / NB_H)   // 3125
#define BINS_W 12500              // u32 words (4 nodes each) = 50000 nodes
#define NBLK1  ((BINS_W + 255) / 256)   // 49
#define NG1    ((N_NODES + 63) / 64)    // 782 gemm1 tiles

typedef unsigned int u32;
typedef unsigned short u16;
typedef unsigned char u8;
typedef __bf16 bf16;
typedef __attribute__((ext_vector_type(8))) __bf16 bf16x8;
typedef __attribute__((ext_vector_type(4))) float f32x4;

// ---------------- per-block partial histograms (u8 packed) + W1 transpose ----------------

__global__ void __launch_bounds__(NT_H) hist_both_kernel(const int* __restrict__ src,
                                                         const int* __restrict__ dst,
                                                         u32* __restrict__ part_s,
                                                         u32* __restrict__ part_d,
                                                         const float* __restrict__ W1,
                                                         bf16* __restrict__ W1t) {
    __shared__ u32 bins[BINS_W];
    const int gb = blockIdx.x;
    if (gb >= 2 * NB_H) {
        int t = (gb - 2 * NB_H) * NT_H + threadIdx.x;   // 0..2047
        int c = t & 63;
        int kq = t >> 6;                                 // 0..31
        int k0 = kq * 8;
        bf16x8 H;
#pragma unroll
        for (int j = 0; j < 8; ++j)
            H[j] = (bf16)W1[(size_t)(k0 + j) * D_H + c];
        *(bf16x8*)&W1t[(size_t)kq * 512 + c * 8] = H;
        return;
    }
    const int b = (gb < NB_H) ? gb : gb - NB_H;
    const int* __restrict__ idx = (gb < NB_H) ? src : dst;
    u32* __restrict__ part = (gb < NB_H) ? part_s : part_d;
    const int e0 = b * EPB;
    const int e1 = (e0 + EPB < N_EDGES) ? e0 + EPB : N_EDGES;
    for (int i = threadIdx.x; i < BINS_W; i += NT_H) bins[i] = 0;
    __syncthreads();
    for (int e = e0 + threadIdx.x; e < e1; e += NT_H) {
        int v = idx[e];
        atomicAdd(&bins[v >> 2], 1u << ((v & 3) * 8));
    }
    __syncthreads();
    for (int i = threadIdx.x; i < BINS_W; i += NT_H)
        part[(size_t)b * BINS_W + i] = bins[i];
}

// ---------------- merged norm/colscan/scan1, u32-vectorized (4 nodes/thread) ----------------

__global__ void norm_both_kernel(const u32* __restrict__ part_s,
                                 u32* __restrict__ part_d,
                                 float* __restrict__ norm_out,
                                 float* __restrict__ norm_in,
                                 int* __restrict__ start,
                                 int* __restrict__ blocksum) {
    __shared__ int tmp[256];
    const int tid = threadIdx.x;
    if (blockIdx.x < NBLK1) {
        const int n4 = blockIdx.x * 256 + tid;
        if (n4 >= BINS_W) return;
        u32 a02 = 0, a13 = 0;
#pragma unroll 8
        for (int b = 0; b < NB_H; ++b) {
            u32 w = part_s[(size_t)b * BINS_W + n4];
            a02 += w & 0x00FF00FFu;
            a13 += (w >> 8) & 0x00FF00FFu;
        }
        float4 no;
        no.x = rsqrtf(fmaxf((float)(a02 & 0xFFFFu), 1.0f));
        no.y = rsqrtf(fmaxf((float)(a13 & 0xFFFFu), 1.0f));
        no.z = rsqrtf(fmaxf((float)(a02 >> 16), 1.0f));
        no.w = rsqrtf(fmaxf((float)(a13 >> 16), 1.0f));
        *(float4*)&norm_out[(size_t)n4 * 4] = no;
    } else {
        const int blk = blockIdx.x - NBLK1;
        const int n4 = blk * 256 + tid;
        const bool ok = (n4 < BINS_W);
        u32 a02 = 0, a13 = 0;
        if (ok) {
#pragma unroll 8
            for (int b = 0; b < NB_H; ++b) {
                size_t i = (size_t)b * BINS_W + n4;
                u32 w = part_d[i];
                u32 off = (a02 & 0xFFu) | ((a13 & 0xFFu) << 8) |
                          (a02 & 0xFF0000u) | ((a13 & 0xFF0000u) << 8);
                part_d[i] = off;
                a02 += w & 0x00FF00FFu;
                a13 += (w >> 8) & 0x00FF00FFu;
            }
        }
        const int d0 = (int)(a02 & 0xFFFFu), d1 = (int)(a13 & 0xFFFFu);
        const int d2 = (int)(a02 >> 16),    d3 = (int)(a13 >> 16);
        if (ok) {
            float4 ni;
            ni.x = rsqrtf(fmaxf((float)d0, 1.0f));
            ni.y = rsqrtf(fmaxf((float)d1, 1.0f));
            ni.z = rsqrtf(fmaxf((float)d2, 1.0f));
            ni.w = rsqrtf(fmaxf((float)d3, 1.0f));
            *(float4*)&norm_in[(size_t)n4 * 4] = ni;
        }
        int s = ok ? (d0 + d1 + d2 + d3) : 0;
        tmp[tid] = s;
        __syncthreads();
        for (int off = 1; off < 256; off <<= 1) {
            int t = (tid >= off) ? tmp[tid - off] : 0;
            __syncthreads();
            tmp[tid] += t;
            __syncthreads();
        }
        if (ok) {
            int P = tmp[tid] - s;
            int4 st;
            st.x = P;
            st.y = P + d0;
            st.z = P + d0 + d1;
            st.w = P + d0 + d1 + d2;
            *(int4*)&start[(size_t)n4 * 4] = st;
        }
        if (tid == 255) blocksum[blk] = tmp[255];
    }
}

// ---------------- merged scan2+scan3 ----------------

__global__ void scan23_kernel(int* __restrict__ start, const int* __restrict__ blocksum) {
    __shared__ int pre[NBLK1];
    if (threadIdx.x == 0) {
        int a = 0;
        for (int b = 0; b < NBLK1; ++b) { pre[b] = a; a += blocksum[b]; }
    }
    __syncthreads();
    const int add = pre[blockIdx.x];
    const int n4 = blockIdx.x * 256 + threadIdx.x;
    if (n4 < BINS_W) {
        int4 v = *(int4*)&start[(size_t)n4 * 4];
        v.x += add; v.y += add; v.z += add; v.w += add;
        *(int4*)&start[(size_t)n4 * 4] = v;
    }
    if (blockIdx.x == 0 && threadIdx.x == 0) start[N_NODES] = N_EDGES;
}

// ---------------- FUSED: scatter (blocks 0..NB_H) + gemm1 (blocks NB_H..NB_H+NG1) ----------------
// No data dependency between the two; scatter is latency-bound, gemm1 is
// MFMA-bound -- co-resident waves overlap (m114).  Scatter blocks first so
// they start immediately.  Dynamic LDS = max(50000, 30720) bytes.
// gemm1 body: identical to round-16 version; threads 256-511 idle through
// barriers (all waves reach every __syncthreads).

#define AST 40   // LDS stride (bf16) for A rows / Wt cols
#define G1T (64 * AST)

__global__ void __launch_bounds__(NT_H) fused_gs_kernel(const float* __restrict__ feat,
                                                        const bf16* __restrict__ W1t,
                                                        const float* __restrict__ norm_out,
                                                        bf16* __restrict__ h1,
                                                        const int* __restrict__ src,
                                                        const int* __restrict__ dst,
                                                        const int* __restrict__ start,
                                                        const u8* __restrict__ off8,
                                                        u16* __restrict__ ssrc) {
    extern __shared__ __align__(16) char smem[];
    const int tid = threadIdx.x;

    if ((int)blockIdx.x < NB_H) {
        // ---------------- scatter body ----------------
        u32* cur = (u32*)smem;
        const int b = blockIdx.x;
        const int e0 = b * EPB;
        const int e1 = (e0 + EPB < N_EDGES) ? e0 + EPB : N_EDGES;
        for (int i = tid; i < BINS_W; i += NT_H) cur[i] = 0;
        __syncthreads();
        for (int e = e0 + tid; e < e1; e += NT_H) {
            int d = dst[e];
            int sh = (d & 3) * 8;
            u32 old = atomicAdd(&cur[d >> 2], 1u << sh);
            int c = (int)((old >> sh) & 0xFFu);
            int pos = start[d] + (int)off8[(size_t)b * N_NODES + d] + c;
            ssrc[pos] = (u16)src[e];
        }
        return;
    }

    // ---------------- gemm1 body (64x64 MFMA tile, 2-term split) ----------------
    bf16* AhB = (bf16*)smem;            // [2][G1T]
    bf16* AlB = AhB + 2 * G1T;
    bf16* WhB = AlB + 2 * G1T;

    const bool act = (tid < 256);
    const int lane = tid & 63;
    const int wv = __builtin_amdgcn_readfirstlane(tid >> 6);   // 0..3 used
    const int n0 = ((int)blockIdx.x - NB_H) * 64;

    const int ar = tid >> 2;
    const int ak = (tid & 3) * 8;
    int nra = n0 + (ar & 63); if (nra >= N_NODES) nra = N_NODES - 1;
    const float* asrc = feat + (size_t)nra * D_IN + ak;

    const int wcol = tid & 63;
    const int wkq = tid >> 6;
    const int wk0 = wkq * 8;

    f32x4 acc[4];
#pragma unroll
    for (int ct = 0; ct < 4; ++ct) acc[ct] = (f32x4){0.f, 0.f, 0.f, 0.f};

    const int fr = lane & 15;
    const int fg = (lane >> 4) * 8;

    auto stageA = [&](int buf, int s) {
        float4 a0 = *(const float4*)(asrc + s * 32);
        float4 a1 = *(const float4*)(asrc + s * 32 + 4);
        float av[8] = {a0.x, a0.y, a0.z, a0.w, a1.x, a1.y, a1.z, a1.w};
        bf16x8 H, L;
#pragma unroll
        for (int j = 0; j < 8; ++j) {
            bf16 h = (bf16)av[j];
            H[j] = h;
            L[j] = (bf16)(av[j] - (float)h);
        }
        *(bf16x8*)&AhB[buf * G1T + ar * AST + ak] = H;
        *(bf16x8*)&AlB[buf * G1T + ar * AST + ak] = L;
    };

    auto stageW = [&](int buf, int s) {
        *(bf16x8*)&WhB[buf * G1T + wcol * AST + wk0] =
            *(const bf16x8*)(W1t + ((size_t)(s * 4 + wkq) * 512 + wcol * 8));
    };

    auto compute = [&](int buf) {
        bf16x8 ah = *(const bf16x8*)&AhB[buf * G1T + (wv * 16 + fr) * AST + fg];
        bf16x8 al = *(const bf16x8*)&AlB[buf * G1T + (wv * 16 + fr) * AST + fg];
#pragma unroll
        for (int ct = 0; ct < 4; ++ct) {
            bf16x8 bh = *(const bf16x8*)&WhB[buf * G1T + (ct * 16 + fr) * AST + fg];
            acc[ct] = __builtin_amdgcn_mfma_f32_16x16x32_bf16(ah, bh, acc[ct], 0, 0, 0);
            acc[ct] = __builtin_amdgcn_mfma_f32_16x16x32_bf16(al, bh, acc[ct], 0, 0, 0);
        }
    };

    if (act) { stageA(0, 0); stageW(0, 0); }
    __syncthreads();
#pragma unroll
    for (int s = 0; s < 8; ++s) {
        const int buf = s & 1;
        if (act) {
            if (s < 7) {
                stageA(buf ^ 1, s + 1);
                stageW(buf ^ 1, s + 1);
            }
            compute(buf);
        }
        __syncthreads();
    }

    if (act) {
        const int orow = n0 + wv * 16 + (lane >> 4) * 4;
        const int ocol = lane & 15;
        float nrm[4];
#pragma unroll
        for (int r = 0; r < 4; ++r)
            nrm[r] = (orow + r < N_NODES) ? norm_out[orow + r] : 0.0f;
#pragma unroll
        for (int ct = 0; ct < 4; ++ct) {
#pragma unroll
            for (int r = 0; r < 4; ++r) {
                if (orow + r < N_NODES)
                    h1[(size_t)(orow + r) * D_H + ct * 16 + ocol] = (bf16)(acc[ct][r] * nrm[r]);
            }
        }
    }
}

// ---------------- agg1: g[n][:] = relu(sum_e h1[ssrc[e]][:] * ni + b1) * no, BF16 out ----------------

__global__ void __launch_bounds__(256) agg1_kernel(const int* __restrict__ start,
                                                   const u16* __restrict__ ssrc,
                                                   const bf16* __restrict__ h1,
                                                   const float* __restrict__ norm_in,
                                                   const float* __restrict__ norm_out,
                                                   const float* __restrict__ b1,
                                                   bf16* __restrict__ g) {
    const int lane = threadIdx.x & 63;
    const int c = lane & 7;
    const int t = lane >> 3;
    const int n = (int)((blockIdx.x * blockDim.x + threadIdx.x) >> 6);
    if (n >= N_NODES) return;

    int beg = __builtin_amdgcn_readfirstlane(start[n]);
    int end = __builtin_amdgcn_readfirstlane(start[n + 1]);
    float acc[8];
#pragma unroll
    for (int j = 0; j < 8; ++j) acc[j] = 0.0f;

    for (int e = beg + t; e < end; e += 16) {
        int s0 = ssrc[e];
        bf16x8 v0 = *(const bf16x8*)(h1 + (size_t)s0 * D_H + c * 8);
        if (e + 8 < end) {
            int s1 = ssrc[e + 8];
            bf16x8 v1 = *(const bf16x8*)(h1 + (size_t)s1 * D_H + c * 8);
#pragma unroll
            for (int j = 0; j < 8; ++j) acc[j] += (float)v1[j];
        }
#pragma unroll
        for (int j = 0; j < 8; ++j) acc[j] += (float)v0[j];
    }
#pragma unroll
    for (int j = 0; j < 8; ++j) {
        acc[j] += __shfl_xor(acc[j], 8);
        acc[j] += __shfl_xor(acc[j], 16);
        acc[j] += __shfl_xor(acc[j], 32);
    }
    if (t == 0) {
        float ni = norm_in[n], no = norm_out[n];
        float4 b0 = *(const float4*)&b1[c * 8];
        float4 b1v = *(const float4*)&b1[c * 8 + 4];
        bf16x8 r;
        r[0] = (bf16)(fmaxf(fmaf(acc[0], ni, b0.x), 0.f) * no);
        r[1] = (bf16)(fmaxf(fmaf(acc[1], ni, b0.y), 0.f) * no);
        r[2] = (bf16)(fmaxf(fmaf(acc[2], ni, b0.z), 0.f) * no);
        r[3] = (bf16)(fmaxf(fmaf(acc[3], ni, b0.w), 0.f) * no);
        r[4] = (bf16)(fmaxf(fmaf(acc[4], ni, b1v.x), 0.f) * no);
        r[5] = (bf16)(fmaxf(fmaf(acc[5], ni, b1v.y), 0.f) * no);
        r[6] = (bf16)(fmaxf(fmaf(acc[6], ni, b1v.z), 0.f) * no);
        r[7] = (bf16)(fmaxf(fmaf(acc[7], ni, b1v.w), 0.f) * no);
        *(bf16x8*)(g + (size_t)n * D_H + c * 8) = r;
    }
}

// ---------------- GEMM2 via MFMA: h2[n][0:40] = g[n,:64] . W2, stride-40 bf16 out ----------------

#define AST2 72  // 64 k + 8 pad, bf16

__global__ void __launch_bounds__(256, 4) gemm2_kernel(const bf16* __restrict__ g,
                                                       const float* __restrict__ W2,
                                                       bf16* __restrict__ h2) {
    __shared__ __align__(16) bf16 Ah[64 * AST2];
    __shared__ __align__(16) bf16 Wh[48 * AST2];
    __shared__ __align__(16) bf16 Wl[48 * AST2];

    const int tid = threadIdx.x;
    const int lane = tid & 63;
    const int wv = __builtin_amdgcn_readfirstlane(tid >> 6);
    const int n0 = blockIdx.x * 64;

    {
        const int ar = tid >> 2;
        const int ak = (tid & 3) * 16;
        int nra = n0 + ar; if (nra >= N_NODES) nra = N_NODES - 1;
        const bf16* asrc = g + (size_t)nra * D_H + ak;
        *(bf16x8*)&Ah[ar * AST2 + ak]     = *(const bf16x8*)(asrc);
        *(bf16x8*)&Ah[ar * AST2 + ak + 8] = *(const bf16x8*)(asrc + 8);
    }
    if (tid < 192) {
        const int col = tid >> 2;
        const int k0 = (tid & 3) * 16;
        float wv16[16];
#pragma unroll
        for (int j = 0; j < 16; ++j)
            wv16[j] = (col < D_O) ? W2[(size_t)(k0 + j) * D_O + col] : 0.0f;
        bf16x8 H0, L0, H1, L1;
#pragma unroll
        for (int j = 0; j < 8; ++j) {
            bf16 h = (bf16)wv16[j];
            H0[j] = h; L0[j] = (bf16)(wv16[j] - (float)h);
            bf16 hb = (bf16)wv16[j + 8];
            H1[j] = hb; L1[j] = (bf16)(wv16[j + 8] - (float)hb);
        }
        *(bf16x8*)&Wh[col * AST2 + k0] = H0;
        *(bf16x8*)&Wh[col * AST2 + k0 + 8] = H1;
        *(bf16x8*)&Wl[col * AST2 + k0] = L0;
        *(bf16x8*)&Wl[col * AST2 + k0 + 8] = L1;
    }
    __syncthreads();

    const int fr = lane & 15;
    const int fg = (lane >> 4) * 8;

    f32x4 acc[3];
#pragma unroll
    for (int ct = 0; ct < 3; ++ct) acc[ct] = (f32x4){0.f, 0.f, 0.f, 0.f};

#pragma unroll
    for (int s = 0; s < 2; ++s) {
        bf16x8 ah = *(const bf16x8*)&Ah[(wv * 16 + fr) * AST2 + s * 32 + fg];
#pragma unroll
        for (int ct = 0; ct < 3; ++ct) {
            bf16x8 bh = *(const bf16x8*)&Wh[(ct * 16 + fr) * AST2 + s * 32 + fg];
            bf16x8 bl = *(const bf16x8*)&Wl[(ct * 16 + fr) * AST2 + s * 32 + fg];
            acc[ct] = __builtin_amdgcn_mfma_f32_16x16x32_bf16(ah, bh, acc[ct], 0, 0, 0);
            acc[ct] = __builtin_amdgcn_mfma_f32_16x16x32_bf16(ah, bl, acc[ct], 0, 0, 0);
        }
    }

    const int orow = n0 + wv * 16 + (lane >> 4) * 4;
    const int ocol = lane & 15;
#pragma unroll
    for (int ct = 0; ct < 3; ++ct) {
        int col = ct * 16 + ocol;
        if (col < D_O) {
#pragma unroll
            for (int r = 0; r < 4; ++r) {
                if (orow + r < N_NODES)
                    h2[(size_t)(orow + r) * D_O + col] = (bf16)acc[ct][r];
            }
        }
    }
}

// ---------------- agg2: out[n][:] = (sum_e h2[ssrc[e]][:]) * ni + b2 ----------------

__global__ void __launch_bounds__(256) agg2_kernel(const int* __restrict__ start,
                                                   const u16* __restrict__ ssrc,
                                                   const bf16* __restrict__ h2,
                                                   const float* __restrict__ norm_in,
                                                   const float* __restrict__ b2,
                                                   float* __restrict__ out) {
    const int lane = threadIdx.x & 63;
    const int c = lane & 7;
    const int t = lane >> 3;
    const int n = (int)((blockIdx.x * blockDim.x + threadIdx.x) >> 6);
    if (n >= N_NODES) return;

    int beg = __builtin_amdgcn_readfirstlane(start[n]);
    int end = __builtin_amdgcn_readfirstlane(start[n + 1]);
    float acc[8];
#pragma unroll
    for (int j = 0; j < 8; ++j) acc[j] = 0.0f;

    if (c < 5) {
        for (int e = beg + t; e < end; e += 16) {
            int s0 = ssrc[e];
            bf16x8 v0 = *(const bf16x8*)(h2 + (size_t)s0 * D_O + c * 8);
            if (e + 8 < end) {
                int s1 = ssrc[e + 8];
                bf16x8 v1 = *(const bf16x8*)(h2 + (size_t)s1 * D_O + c * 8);
#pragma unroll
                for (int j = 0; j < 8; ++j) acc[j] += (float)v1[j];
            }
#pragma unroll
            for (int j = 0; j < 8; ++j) acc[j] += (float)v0[j];
        }
    }
#pragma unroll
    for (int j = 0; j < 8; ++j) {
        acc[j] += __shfl_xor(acc[j], 8);
        acc[j] += __shfl_xor(acc[j], 16);
        acc[j] += __shfl_xor(acc[j], 32);
    }
    if (t == 0 && c < 5) {
        float ni = norm_in[n];
        float4 b0 = *(const float4*)&b2[c * 8];
        float4 b1v = *(const float4*)&b2[c * 8 + 4];
        float* op = out + (size_t)n * D_O + c * 8;
        *(float4*)(op) = make_float4(fmaf(acc[0], ni, b0.x), fmaf(acc[1], ni, b0.y),
                                     fmaf(acc[2], ni, b0.z), fmaf(acc[3], ni, b0.w));
        *(float4*)(op + 4) = make_float4(fmaf(acc[4], ni, b1v.x), fmaf(acc[5], ni, b1v.y),
                                         fmaf(acc[6], ni, b1v.z), fmaf(acc[7], ni, b1v.w));
    }
}

// ----------------------------------------------------------------------------

static inline char* alignup(char* p, size_t a) {
    return (char*)(((uintptr_t)p + a - 1) & ~(uintptr_t)(a - 1));
}

extern "C" void kernel_launch(void* const* d_in, const int* in_sizes, int n_in,
                              void* d_out, int out_size, void* d_ws, size_t ws_size,
                              hipStream_t stream) {
    const float* feat = (const float*)d_in[0];
    const int*   src  = (const int*)d_in[1];
    const int*   dst  = (const int*)d_in[2];
    const float* W1   = (const float*)d_in[3];
    const float* b1   = (const float*)d_in[4];
    const float* W2   = (const float*)d_in[5];
    const float* b2   = (const float*)d_in[6];
    float* out = (float*)d_out;

    char* p = alignup((char*)d_ws, 256);
    int*   start    = (int*)p;    p = alignup(p + (N_NODES + 1) * 4, 256);
    int*   blocksum = (int*)p;    p = alignup(p + 256 * 4, 256);
    float* norm_out = (float*)p;  p = alignup(p + N_NODES * 4, 256);
    float* norm_in  = (float*)p;  p = alignup(p + N_NODES * 4, 256);
    bf16*  W1t      = (bf16*)p;   p = alignup(p + (size_t)D_IN * D_H * 2, 256);
    u16*   ssrc     = (u16*)p;    p = alignup(p + N_EDGES * 2, 256);
    bf16*  h1       = (bf16*)p;   p = alignup(p + (size_t)N_NODES * D_H * 2, 256);
    bf16*  g        = (bf16*)p;   p = alignup(p + (size_t)N_NODES * D_H * 2, 256);
    bf16*  h2q      = (bf16*)p;   p = alignup(p + (size_t)N_NODES * D_O * 2, 256);
    u32*   part_s   = (u32*)p;    p = alignup(p + (size_t)NB_H * BINS_W * 4, 256);
    u32*   part_d   = (u32*)p;    p = alignup(p + (size_t)NB_H * BINS_W * 4, 256);

    hist_both_kernel<<<2 * NB_H + 4, NT_H, 0, stream>>>(src, dst, part_s, part_d, W1, W1t);
    norm_both_kernel<<<2 * NBLK1, 256, 0, stream>>>(part_s, part_d, norm_out, norm_in,
                                                    start, blocksum);
    scan23_kernel<<<NBLK1, 256, 0, stream>>>(start, blocksum);

    // fused scatter (blocks 0..NB_H) + gemm1 (blocks NB_H..NB_H+NG1)
    fused_gs_kernel<<<NB_H + NG1, NT_H, 50176, stream>>>(feat, W1t, norm_out, h1,
                                                         src, dst, start,
                                                         (const u8*)part_d, ssrc);

    agg1_kernel<<<(N_NODES + 3) / 4, 256, 0, stream>>>(start, ssrc, h1, norm_in, norm_out, b1, g);

    gemm2_kernel<<<(N_NODES + 63) / 64, 256, 0, stream>>>(g, W2, h2q);
    agg2_kernel<<<(N_NODES + 3) / 4, 256, 0, stream>>>(start, ssrc, h2q, norm_in, b2, out);
}

// Round 19
// 113.936 us; speedup vs baseline: 1.0035x; 1.0035x over previous
//
#include <hip/hip_runtime.h>
#include <stdint.h>

#define N_NODES 50000
#define N_EDGES 800000
#define D_IN    256
#define D_H     64
#define D_O     40

// CSR build geometry: 256 blocks x 3125-edge slices; ONE pass -- u4 counts
// packed 8-per-u32 in 25 KB LDS cover all 50000 nodes (per-slice per-node
// count is Poisson(0.0625), max ~6, P(>=16) ~ 1e-33).
#define NB_H   256
#define NT_H   512
#define EPB    (N_EDGES / NB_H)   // 3125
#define BINS_W 12500              // u32 words (4 nodes each, u8) = 50000 nodes
#define BINS_N4 6250              // u32 words (8 nodes each, u4)
#define NBLK1  ((BINS_W + 255) / 256)   // 49

typedef unsigned int u32;
typedef unsigned short u16;
typedef unsigned char u8;
typedef __bf16 bf16;
typedef __attribute__((ext_vector_type(8))) __bf16 bf16x8;
typedef __attribute__((ext_vector_type(4))) float f32x4;

// ---------------- per-block partial histograms (u4 LDS, u8-packed output) + W1 transpose ----------------

__global__ void __launch_bounds__(NT_H) hist_both_kernel(const int* __restrict__ src,
                                                         const int* __restrict__ dst,
                                                         u32* __restrict__ part_s,
                                                         u32* __restrict__ part_d,
                                                         const float* __restrict__ W1,
                                                         bf16* __restrict__ W1t) {
    __shared__ u32 bins4[BINS_N4];
    const int gb = blockIdx.x;
    if (gb >= 2 * NB_H) {
        int t = (gb - 2 * NB_H) * NT_H + threadIdx.x;   // 0..2047
        int c = t & 63;
        int kq = t >> 6;                                 // 0..31
        int k0 = kq * 8;
        bf16x8 H;
#pragma unroll
        for (int j = 0; j < 8; ++j)
            H[j] = (bf16)W1[(size_t)(k0 + j) * D_H + c];
        *(bf16x8*)&W1t[(size_t)kq * 512 + c * 8] = H;
        return;
    }
    const int b = (gb < NB_H) ? gb : gb - NB_H;
    const int* __restrict__ idx = (gb < NB_H) ? src : dst;
    u32* __restrict__ part = (gb < NB_H) ? part_s : part_d;
    const int e0 = b * EPB;
    const int e1 = (e0 + EPB < N_EDGES) ? e0 + EPB : N_EDGES;
    for (int i = threadIdx.x; i < BINS_N4; i += NT_H) bins4[i] = 0;
    __syncthreads();
    for (int e = e0 + threadIdx.x; e < e1; e += NT_H) {
        int v = idx[e];
        atomicAdd(&bins4[v >> 3], 1u << ((v & 7) * 4));
    }
    __syncthreads();
    // expand u4 nibbles -> u8-packed output words (4 nodes per u32)
    for (int i = threadIdx.x; i < BINS_W; i += NT_H) {
        u32 x = (bins4[i >> 1] >> ((i & 1) * 16)) & 0xFFFFu;
        u32 out = (x & 0xFu) | ((x & 0xF0u) << 4) | ((x & 0xF00u) << 8) | ((x & 0xF000u) << 12);
        part[(size_t)b * BINS_W + i] = out;
    }
}

// ---------------- merged norm/colscan/scan1, u32-vectorized (4 nodes/thread) ----------------

__global__ void norm_both_kernel(const u32* __restrict__ part_s,
                                 u32* __restrict__ part_d,
                                 float* __restrict__ norm_out,
                                 float* __restrict__ norm_in,
                                 int* __restrict__ start,
                                 int* __restrict__ blocksum) {
    __shared__ int tmp[256];
    const int tid = threadIdx.x;
    if (blockIdx.x < NBLK1) {
        const int n4 = blockIdx.x * 256 + tid;
        if (n4 >= BINS_W) return;
        u32 a02 = 0, a13 = 0;
#pragma unroll 8
        for (int b = 0; b < NB_H; ++b) {
            u32 w = part_s[(size_t)b * BINS_W + n4];
            a02 += w & 0x00FF00FFu;
            a13 += (w >> 8) & 0x00FF00FFu;
        }
        float4 no;
        no.x = rsqrtf(fmaxf((float)(a02 & 0xFFFFu), 1.0f));
        no.y = rsqrtf(fmaxf((float)(a13 & 0xFFFFu), 1.0f));
        no.z = rsqrtf(fmaxf((float)(a02 >> 16), 1.0f));
        no.w = rsqrtf(fmaxf((float)(a13 >> 16), 1.0f));
        *(float4*)&norm_out[(size_t)n4 * 4] = no;
    } else {
        const int blk = blockIdx.x - NBLK1;
        const int n4 = blk * 256 + tid;
        const bool ok = (n4 < BINS_W);
        u32 a02 = 0, a13 = 0;
        if (ok) {
#pragma unroll 8
            for (int b = 0; b < NB_H; ++b) {
                size_t i = (size_t)b * BINS_W + n4;
                u32 w = part_d[i];
                u32 off = (a02 & 0xFFu) | ((a13 & 0xFFu) << 8) |
                          (a02 & 0xFF0000u) | ((a13 & 0xFF0000u) << 8);
                part_d[i] = off;
                a02 += w & 0x00FF00FFu;
                a13 += (w >> 8) & 0x00FF00FFu;
            }
        }
        const int d0 = (int)(a02 & 0xFFFFu), d1 = (int)(a13 & 0xFFFFu);
        const int d2 = (int)(a02 >> 16),    d3 = (int)(a13 >> 16);
        if (ok) {
            float4 ni;
            ni.x = rsqrtf(fmaxf((float)d0, 1.0f));
            ni.y = rsqrtf(fmaxf((float)d1, 1.0f));
            ni.z = rsqrtf(fmaxf((float)d2, 1.0f));
            ni.w = rsqrtf(fmaxf((float)d3, 1.0f));
            *(float4*)&norm_in[(size_t)n4 * 4] = ni;
        }
        int s = ok ? (d0 + d1 + d2 + d3) : 0;
        tmp[tid] = s;
        __syncthreads();
        for (int off = 1; off < 256; off <<= 1) {
            int t = (tid >= off) ? tmp[tid - off] : 0;
            __syncthreads();
            tmp[tid] += t;
            __syncthreads();
        }
        if (ok) {
            int P = tmp[tid] - s;
            int4 st;
            st.x = P;
            st.y = P + d0;
            st.z = P + d0 + d1;
            st.w = P + d0 + d1 + d2;
            *(int4*)&start[(size_t)n4 * 4] = st;
        }
        if (tid == 255) blocksum[blk] = tmp[255];
    }
}

// ---------------- merged scan2+scan3 ----------------

__global__ void scan23_kernel(int* __restrict__ start, const int* __restrict__ blocksum) {
    __shared__ int pre[NBLK1];
    if (threadIdx.x == 0) {
        int a = 0;
        for (int b = 0; b < NBLK1; ++b) { pre[b] = a; a += blocksum[b]; }
    }
    __syncthreads();
    const int add = pre[blockIdx.x];
    const int n4 = blockIdx.x * 256 + threadIdx.x;
    if (n4 < BINS_W) {
        int4 v = *(int4*)&start[(size_t)n4 * 4];
        v.x += add; v.y += add; v.z += add; v.w += add;
        *(int4*)&start[(size_t)n4 * 4] = v;
    }
    if (blockIdx.x == 0 && threadIdx.x == 0) start[N_NODES] = N_EDGES;
}

// ---------------- scatter edges into CSR order (u4 packed LDS cursors) ----------------

__global__ void __launch_bounds__(NT_H) scatter2_kernel(const int* __restrict__ src,
                                                        const int* __restrict__ dst,
                                                        const int* __restrict__ start,
                                                        const u8* __restrict__ off8,
                                                        u16* __restrict__ ssrc) {
    __shared__ u32 cur4[BINS_N4];
    const int b = blockIdx.x;
    const int e0 = b * EPB;
    const int e1 = (e0 + EPB < N_EDGES) ? e0 + EPB : N_EDGES;
    for (int i = threadIdx.x; i < BINS_N4; i += NT_H) cur4[i] = 0;
    __syncthreads();
    for (int e = e0 + threadIdx.x; e < e1; e += NT_H) {
        int d = dst[e];
        int sh = (d & 7) * 4;
        u32 old = atomicAdd(&cur4[d >> 3], 1u << sh);
        int c = (int)((old >> sh) & 0xFu);
        int pos = start[d] + (int)off8[(size_t)b * N_NODES + d] + c;
        ssrc[pos] = (u16)src[e];
    }
}

// ---------------- GEMM1 via MFMA, 2-term split (A = hi+lo exact, W plain bf16) ----------------
// 64x64 per block, 4 waves, K in 8 dbuf steps of 32.  x*w = ah*wh + al*wh.
// W staged via coalesced bf16x8 copies from pre-transposed W1t.
// Output BF16 (stride 64).  C/D: col=lane&15, row=(lane>>4)*4+reg (HW-verified).

#define AST 40   // LDS stride (bf16) for A rows / Wt cols

__global__ void __launch_bounds__(256, 4) gemm1_kernel(const float* __restrict__ feat,
                                                       const bf16* __restrict__ W1t,
                                                       const float* __restrict__ norm_out,
                                                       bf16* __restrict__ h1) {
    __shared__ __align__(16) bf16 Ah[2][64 * AST];
    __shared__ __align__(16) bf16 Al[2][64 * AST];
    __shared__ __align__(16) bf16 Wh[2][64 * AST];

    const int tid = threadIdx.x;
    const int lane = tid & 63;
    const int wv = __builtin_amdgcn_readfirstlane(tid >> 6);
    const int n0 = blockIdx.x * 64;

    const int ar = tid >> 2;
    const int ak = (tid & 3) * 8;
    int nra = n0 + ar; if (nra >= N_NODES) nra = N_NODES - 1;
    const float* asrc = feat + (size_t)nra * D_IN + ak;

    const int wcol = tid & 63;
    const int wkq = tid >> 6;
    const int wk0 = wkq * 8;

    f32x4 acc[4];
#pragma unroll
    for (int ct = 0; ct < 4; ++ct) acc[ct] = (f32x4){0.f, 0.f, 0.f, 0.f};

    const int fr = lane & 15;
    const int fg = (lane >> 4) * 8;

    auto stageA = [&](int buf, int s) {
        float4 a0 = *(const float4*)(asrc + s * 32);
        float4 a1 = *(const float4*)(asrc + s * 32 + 4);
        float av[8] = {a0.x, a0.y, a0.z, a0.w, a1.x, a1.y, a1.z, a1.w};
        bf16x8 H, L;
#pragma unroll
        for (int j = 0; j < 8; ++j) {
            bf16 h = (bf16)av[j];
            H[j] = h;
            L[j] = (bf16)(av[j] - (float)h);
        }
        *(bf16x8*)&Ah[buf][ar * AST + ak] = H;
        *(bf16x8*)&Al[buf][ar * AST + ak] = L;
    };

    auto stageW = [&](int buf, int s) {
        *(bf16x8*)&Wh[buf][wcol * AST + wk0] =
            *(const bf16x8*)(W1t + ((size_t)(s * 4 + wkq) * 512 + wcol * 8));
    };

    auto compute = [&](int buf) {
        bf16x8 ah = *(const bf16x8*)&Ah[buf][(wv * 16 + fr) * AST + fg];
        bf16x8 al = *(const bf16x8*)&Al[buf][(wv * 16 + fr) * AST + fg];
#pragma unroll
        for (int ct = 0; ct < 4; ++ct) {
            bf16x8 bh = *(const bf16x8*)&Wh[buf][(ct * 16 + fr) * AST + fg];
            acc[ct] = __builtin_amdgcn_mfma_f32_16x16x32_bf16(ah, bh, acc[ct], 0, 0, 0);
            acc[ct] = __builtin_amdgcn_mfma_f32_16x16x32_bf16(al, bh, acc[ct], 0, 0, 0);
        }
    };

    stageA(0, 0);
    stageW(0, 0);
    __syncthreads();
#pragma unroll
    for (int s = 0; s < 8; ++s) {
        const int buf = s & 1;
        if (s < 7) {
            stageA(buf ^ 1, s + 1);
            stageW(buf ^ 1, s + 1);
        }
        compute(buf);
        __syncthreads();
    }

    const int orow = n0 + wv * 16 + (lane >> 4) * 4;
    const int ocol = lane & 15;
    float nrm[4];
#pragma unroll
    for (int r = 0; r < 4; ++r)
        nrm[r] = (orow + r < N_NODES) ? norm_out[orow + r] : 0.0f;
#pragma unroll
    for (int ct = 0; ct < 4; ++ct) {
#pragma unroll
        for (int r = 0; r < 4; ++r) {
            if (orow + r < N_NODES)
                h1[(size_t)(orow + r) * D_H + ct * 16 + ocol] = (bf16)(acc[ct][r] * nrm[r]);
        }
    }
}

// ---------------- agg1: g[n][:] = relu(sum_e h1[ssrc[e]][:] * ni + b1) * no, BF16 out ----------------

__global__ void __launch_bounds__(256) agg1_kernel(const int* __restrict__ start,
                                                   const u16* __restrict__ ssrc,
                                                   const bf16* __restrict__ h1,
                                                   const float* __restrict__ norm_in,
                                                   const float* __restrict__ norm_out,
                                                   const float* __restrict__ b1,
                                                   bf16* __restrict__ g) {
    const int lane = threadIdx.x & 63;
    const int c = lane & 7;
    const int t = lane >> 3;
    const int n = (int)((blockIdx.x * blockDim.x + threadIdx.x) >> 6);
    if (n >= N_NODES) return;

    int beg = __builtin_amdgcn_readfirstlane(start[n]);
    int end = __builtin_amdgcn_readfirstlane(start[n + 1]);
    float acc[8];
#pragma unroll
    for (int j = 0; j < 8; ++j) acc[j] = 0.0f;

    for (int e = beg + t; e < end; e += 16) {
        int s0 = ssrc[e];
        bf16x8 v0 = *(const bf16x8*)(h1 + (size_t)s0 * D_H + c * 8);
        if (e + 8 < end) {
            int s1 = ssrc[e + 8];
            bf16x8 v1 = *(const bf16x8*)(h1 + (size_t)s1 * D_H + c * 8);
#pragma unroll
            for (int j = 0; j < 8; ++j) acc[j] += (float)v1[j];
        }
#pragma unroll
        for (int j = 0; j < 8; ++j) acc[j] += (float)v0[j];
    }
#pragma unroll
    for (int j = 0; j < 8; ++j) {
        acc[j] += __shfl_xor(acc[j], 8);
        acc[j] += __shfl_xor(acc[j], 16);
        acc[j] += __shfl_xor(acc[j], 32);
    }
    if (t == 0) {
        float ni = norm_in[n], no = norm_out[n];
        float4 b0 = *(const float4*)&b1[c * 8];
        float4 b1v = *(const float4*)&b1[c * 8 + 4];
        bf16x8 r;
        r[0] = (bf16)(fmaxf(fmaf(acc[0], ni, b0.x), 0.f) * no);
        r[1] = (bf16)(fmaxf(fmaf(acc[1], ni, b0.y), 0.f) * no);
        r[2] = (bf16)(fmaxf(fmaf(acc[2], ni, b0.z), 0.f) * no);
        r[3] = (bf16)(fmaxf(fmaf(acc[3], ni, b0.w), 0.f) * no);
        r[4] = (bf16)(fmaxf(fmaf(acc[4], ni, b1v.x), 0.f) * no);
        r[5] = (bf16)(fmaxf(fmaf(acc[5], ni, b1v.y), 0.f) * no);
        r[6] = (bf16)(fmaxf(fmaf(acc[6], ni, b1v.z), 0.f) * no);
        r[7] = (bf16)(fmaxf(fmaf(acc[7], ni, b1v.w), 0.f) * no);
        *(bf16x8*)(g + (size_t)n * D_H + c * 8) = r;
    }
}

// ---------------- GEMM2 via MFMA: h2[n][0:40] = g[n,:64] . W2, stride-40 bf16 out ----------------

#define AST2 72  // 64 k + 8 pad, bf16

__global__ void __launch_bounds__(256, 4) gemm2_kernel(const bf16* __restrict__ g,
                                                       const float* __restrict__ W2,
                                                       bf16* __restrict__ h2) {
    __shared__ __align__(16) bf16 Ah[64 * AST2];
    __shared__ __align__(16) bf16 Wh[48 * AST2];
    __shared__ __align__(16) bf16 Wl[48 * AST2];

    const int tid = threadIdx.x;
    const int lane = tid & 63;
    const int wv = __builtin_amdgcn_readfirstlane(tid >> 6);
    const int n0 = blockIdx.x * 64;

    {
        const int ar = tid >> 2;
        const int ak = (tid & 3) * 16;
        int nra = n0 + ar; if (nra >= N_NODES) nra = N_NODES - 1;
        const bf16* asrc = g + (size_t)nra * D_H + ak;
        *(bf16x8*)&Ah[ar * AST2 + ak]     = *(const bf16x8*)(asrc);
        *(bf16x8*)&Ah[ar * AST2 + ak + 8] = *(const bf16x8*)(asrc + 8);
    }
    if (tid < 192) {
        const int col = tid >> 2;
        const int k0 = (tid & 3) * 16;
        float wv16[16];
#pragma unroll
        for (int j = 0; j < 16; ++j)
            wv16[j] = (col < D_O) ? W2[(size_t)(k0 + j) * D_O + col] : 0.0f;
        bf16x8 H0, L0, H1, L1;
#pragma unroll
        for (int j = 0; j < 8; ++j) {
            bf16 h = (bf16)wv16[j];
            H0[j] = h; L0[j] = (bf16)(wv16[j] - (float)h);
            bf16 hb = (bf16)wv16[j + 8];
            H1[j] = hb; L1[j] = (bf16)(wv16[j + 8] - (float)hb);
        }
        *(bf16x8*)&Wh[col * AST2 + k0] = H0;
        *(bf16x8*)&Wh[col * AST2 + k0 + 8] = H1;
        *(bf16x8*)&Wl[col * AST2 + k0] = L0;
        *(bf16x8*)&Wl[col * AST2 + k0 + 8] = L1;
    }
    __syncthreads();

    const int fr = lane & 15;
    const int fg = (lane >> 4) * 8;

    f32x4 acc[3];
#pragma unroll
    for (int ct = 0; ct < 3; ++ct) acc[ct] = (f32x4){0.f, 0.f, 0.f, 0.f};

#pragma unroll
    for (int s = 0; s < 2; ++s) {
        bf16x8 ah = *(const bf16x8*)&Ah[(wv * 16 + fr) * AST2 + s * 32 + fg];
#pragma unroll
        for (int ct = 0; ct < 3; ++ct) {
            bf16x8 bh = *(const bf16x8*)&Wh[(ct * 16 + fr) * AST2 + s * 32 + fg];
            bf16x8 bl = *(const bf16x8*)&Wl[(ct * 16 + fr) * AST2 + s * 32 + fg];
            acc[ct] = __builtin_amdgcn_mfma_f32_16x16x32_bf16(ah, bh, acc[ct], 0, 0, 0);
            acc[ct] = __builtin_amdgcn_mfma_f32_16x16x32_bf16(ah, bl, acc[ct], 0, 0, 0);
        }
    }

    const int orow = n0 + wv * 16 + (lane >> 4) * 4;
    const int ocol = lane & 15;
#pragma unroll
    for (int ct = 0; ct < 3; ++ct) {
        int col = ct * 16 + ocol;
        if (col < D_O) {
#pragma unroll
            for (int r = 0; r < 4; ++r) {
                if (orow + r < N_NODES)
                    h2[(size_t)(orow + r) * D_O + col] = (bf16)acc[ct][r];
            }
        }
    }
}

// ---------------- agg2: out[n][:] = (sum_e h2[ssrc[e]][:]) * ni + b2 ----------------

__global__ void __launch_bounds__(256) agg2_kernel(const int* __restrict__ start,
                                                   const u16* __restrict__ ssrc,
                                                   const bf16* __restrict__ h2,
                                                   const float* __restrict__ norm_in,
                                                   const float* __restrict__ b2,
                                                   float* __restrict__ out) {
    const int lane = threadIdx.x & 63;
    const int c = lane & 7;
    const int t = lane >> 3;
    const int n = (int)((blockIdx.x * blockDim.x + threadIdx.x) >> 6);
    if (n >= N_NODES) return;

    int beg = __builtin_amdgcn_readfirstlane(start[n]);
    int end = __builtin_amdgcn_readfirstlane(start[n + 1]);
    float acc[8];
#pragma unroll
    for (int j = 0; j < 8; ++j) acc[j] = 0.0f;

    if (c < 5) {
        for (int e = beg + t; e < end; e += 16) {
            int s0 = ssrc[e];
            bf16x8 v0 = *(const bf16x8*)(h2 + (size_t)s0 * D_O + c * 8);
            if (e + 8 < end) {
                int s1 = ssrc[e + 8];
                bf16x8 v1 = *(const bf16x8*)(h2 + (size_t)s1 * D_O + c * 8);
#pragma unroll
                for (int j = 0; j < 8; ++j) acc[j] += (float)v1[j];
            }
#pragma unroll
            for (int j = 0; j < 8; ++j) acc[j] += (float)v0[j];
        }
    }
#pragma unroll
    for (int j = 0; j < 8; ++j) {
        acc[j] += __shfl_xor(acc[j], 8);
        acc[j] += __shfl_xor(acc[j], 16);
        acc[j] += __shfl_xor(acc[j], 32);
    }
    if (t == 0 && c < 5) {
        float ni = norm_in[n];
        float4 b0 = *(const float4*)&b2[c * 8];
        float4 b1v = *(const float4*)&b2[c * 8 + 4];
        float* op = out + (size_t)n * D_O + c * 8;
        *(float4*)(op) = make_float4(fmaf(acc[0], ni, b0.x), fmaf(acc[1], ni, b0.y),
                                     fmaf(acc[2], ni, b0.z), fmaf(acc[3], ni, b0.w));
        *(float4*)(op + 4) = make_float4(fmaf(acc[4], ni, b1v.x), fmaf(acc[5], ni, b1v.y),
                                         fmaf(acc[6], ni, b1v.z), fmaf(acc[7], ni, b1v.w));
    }
}

// ----------------------------------------------------------------------------

static inline char* alignup(char* p, size_t a) {
    return (char*)(((uintptr_t)p + a - 1) & ~(uintptr_t)(a - 1));
}

extern "C" void kernel_launch(void* const* d_in, const int* in_sizes, int n_in,
                              void* d_out, int out_size, void* d_ws, size_t ws_size,
                              hipStream_t stream) {
    const float* feat = (const float*)d_in[0];
    const int*   src  = (const int*)d_in[1];
    const int*   dst  = (const int*)d_in[2];
    const float* W1   = (const float*)d_in[3];
    const float* b1   = (const float*)d_in[4];
    const float* W2   = (const float*)d_in[5];
    const float* b2   = (const float*)d_in[6];
    float* out = (float*)d_out;

    char* p = alignup((char*)d_ws, 256);
    int*   start    = (int*)p;    p = alignup(p + (N_NODES + 1) * 4, 256);
    int*   blocksum = (int*)p;    p = alignup(p + 256 * 4, 256);
    float* norm_out = (float*)p;  p = alignup(p + N_NODES * 4, 256);
    float* norm_in  = (float*)p;  p = alignup(p + N_NODES * 4, 256);
    bf16*  W1t      = (bf16*)p;   p = alignup(p + (size_t)D_IN * D_H * 2, 256);
    u16*   ssrc     = (u16*)p;    p = alignup(p + N_EDGES * 2, 256);
    bf16*  h1       = (bf16*)p;   p = alignup(p + (size_t)N_NODES * D_H * 2, 256);
    bf16*  g        = (bf16*)p;   p = alignup(p + (size_t)N_NODES * D_H * 2, 256);
    bf16*  h2q      = (bf16*)p;   p = alignup(p + (size_t)N_NODES * D_O * 2, 256);
    u32*   part_s   = (u32*)p;    p = alignup(p + (size_t)NB_H * BINS_W * 4, 256);
    u32*   part_d   = (u32*)p;    p = alignup(p + (size_t)NB_H * BINS_W * 4, 256);

    hist_both_kernel<<<2 * NB_H + 4, NT_H, 0, stream>>>(src, dst, part_s, part_d, W1, W1t);
    norm_both_kernel<<<2 * NBLK1, 256, 0, stream>>>(part_s, part_d, norm_out, norm_in,
                                                    start, blocksum);
    scan23_kernel<<<NBLK1, 256, 0, stream>>>(start, blocksum);

    scatter2_kernel<<<NB_H, NT_H, 0, stream>>>(src, dst, start, (const u8*)part_d, ssrc);

    gemm1_kernel<<<(N_NODES + 63) / 64, 256, 0, stream>>>(feat, W1t, norm_out, h1);
    agg1_kernel<<<(N_NODES + 3) / 4, 256, 0, stream>>>(start, ssrc, h1, norm_in, norm_out, b1, g);

    gemm2_kernel<<<(N_NODES + 63) / 64, 256, 0, stream>>>(g, W2, h2q);
    agg2_kernel<<<(N_NODES + 3) / 4, 256, 0, stream>>>(start, ssrc, h2q, norm_in, b2, out);
}